// Round 10
// baseline (200.598 us; speedup 1.0000x reference)
//
#include <hip/hip_runtime.h>

#define N_NODES 100000
#define N_EDGES 1600000
#define IN_F 64
#define HID 128
#define HID2 64
#define NCLS 10

#define NRANGE 8
#define RANGE_NODES ((N_NODES + NRANGE - 1) / NRANGE)   // 12500

// fixed-stride padded CSR: 64 slots per node (max Poisson-16 degree ~45)
#define SEG 64

// per-bucket capacity for edge binning (mean 200k, std ~420)
#define CAP 210000
#define EBA 6250                       // edges per binA block (256 blocks)
#define PBCHUNK ((CAP + 63) / 64)      // binB entries per block (64 chunks/range)

typedef __attribute__((ext_vector_type(8))) short bfrag;
typedef __attribute__((ext_vector_type(4))) float f32x4;

// ---- RNE float->bf16 ----
__device__ __forceinline__ unsigned short bf_rne(float f) {
  unsigned int u = __float_as_uint(f);
  u += 0x7fffu + ((u >> 16) & 1u);
  return (unsigned short)(u >> 16);
}

// ---------------- cast x -> bf16 (8 floats / thread) ----------------
__global__ __launch_bounds__(256) void cast_k(const float* __restrict__ x,
                                              unsigned short* __restrict__ xb) {
  int i = blockIdx.x * blockDim.x + threadIdx.x;   // 8-float unit
  const float4* xf4 = (const float4*)x;
  float4 a = xf4[2 * i];
  float4 b = xf4[2 * i + 1];
  ushort4 o0, o1;
  o0.x = bf_rne(a.x); o0.y = bf_rne(a.y); o0.z = bf_rne(a.z); o0.w = bf_rne(a.w);
  o1.x = bf_rne(b.x); o1.y = bf_rne(b.y); o1.z = bf_rne(b.z); o1.w = bf_rne(b.w);
  ushort4* ob = (ushort4*)xb;
  ob[2 * i] = o0;
  ob[2 * i + 1] = o1;
}

// ---------------- W1/W2 -> bf16 transposed [out][k] (once) ----------------
__global__ __launch_bounds__(256) void wtrans_k(const float* __restrict__ W1,
                                                const float* __restrict__ W2,
                                                unsigned short* __restrict__ W1t,
                                                unsigned short* __restrict__ W2t) {
  int i = blockIdx.x * 256 + threadIdx.x;          // 0 .. 16383
  if (i < IN_F * HID) {                            // W1t[j][k] = W1[k][j]
    int j = i >> 6, k = i & 63;                    // j<128, k<64
    W1t[i] = bf_rne(W1[k * HID + j]);
  } else {
    int i2 = i - IN_F * HID;                       // W2t[j][k] = W2[k][j]
    int j = i2 >> 7, k = i2 & 127;                 // j<64, k<128
    W2t[i2] = bf_rne(W2[k * HID2 + j]);
  }
}

// ---------------- cursor init: cursors[n] = n*SEG ----------------
__global__ __launch_bounds__(256) void curs_init_k(int* __restrict__ cursors) {
  int n = blockIdx.x * blockDim.x + threadIdx.x;
  if (n < N_NODES) cursors[n] = n * SEG;
}

// ---- binA: bin edges into 8 dst-range buckets as (dst,src) int2 pairs ----
// Block-aggregated bucket cursors: LDS histogram -> 8 global atomics/block ->
// dense contiguous-per-block bucket writes (no line amplification).
__global__ __launch_bounds__(256) void binA_k(const int* __restrict__ row,
                                              const int* __restrict__ col,
                                              int* __restrict__ bcnt,
                                              int2* __restrict__ pairs) {
  __shared__ int hcnt[NRANGE];
  __shared__ int hbase[NRANGE];
  int t = threadIdx.x;
  if (t < NRANGE) hcnt[t] = 0;
  __syncthreads();
  int e0 = blockIdx.x * EBA;
  int e1 = e0 + EBA;
  for (int e = e0 + t; e < e1; e += 256) {
    int b = col[e] / RANGE_NODES;
    atomicAdd(&hcnt[b], 1);
  }
  __syncthreads();
  if (t < NRANGE) {
    hbase[t] = atomicAdd(&bcnt[t], hcnt[t]);
    hcnt[t] = 0;
  }
  __syncthreads();
  for (int e = e0 + t; e < e1; e += 256) {
    int dst = col[e];
    int src = row[e];
    int b = dst / RANGE_NODES;
    int pos = hbase[b] + atomicAdd(&hcnt[b], 1);
    pairs[(size_t)b * CAP + pos] = make_int2(dst, src);
  }
}

// ---- binB: XCD-local scatter from bucket r into fixed-stride csr slots ----
// Block (r = bid&7 -> XCD r, j = bid>>3). L2 footprint per XCD: 1.6 MB
// bucket stream + 3.2 MB dirty csr region -> lines survive to full coverage.
__global__ __launch_bounds__(256) void binB_k(const int2* __restrict__ pairs,
                                              const int* __restrict__ bcnt,
                                              int* __restrict__ cursors,
                                              int* __restrict__ csr_src) {
  int r = blockIdx.x & (NRANGE - 1);
  int j = blockIdx.x >> 3;
  int cnt = bcnt[r];
  int i0 = j * PBCHUNK;
  int i1 = i0 + PBCHUNK;
  if (i1 > cnt) i1 = cnt;
  const int2* bp = pairs + (size_t)r * CAP;
  for (int i = i0 + threadIdx.x; i < i1; i += 256) {
    int2 p = bp[i];
    int pos = atomicAdd(&cursors[p.x], 1);
    csr_src[pos] = p.y;
  }
}

// ---------- bf16 padded gather: rows of 64 bf16 = 128 B = 16 uint2 chunks --
__device__ __forceinline__ float4 gather_bf16(const uint2* __restrict__ vb,
                                              const int* __restrict__ csr,
                                              int s, int e2, int padc,
                                              int eg, int fc) {
  float ax = 0.f, ay = 0.f, az = 0.f, aw = 0.f;
  const int4* csr4 = (const int4*)csr;
#define ACCUM(w)                                                    \
  {                                                                 \
    ax += __uint_as_float((w).x << 16);                             \
    ay += __uint_as_float((w).x & 0xffff0000u);                     \
    az += __uint_as_float((w).y << 16);                             \
    aw += __uint_as_float((w).y & 0xffff0000u);                     \
  }
  int p = s;
  for (; p + 32 <= e2; p += 32) {   // 2 units: 8 gathers in flight
    int4 iA = csr4[(p >> 2) + eg];
    int4 iB = csr4[((p + 16) >> 2) + eg];
    uint2 a0 = vb[(size_t)iA.x * 16 + fc];
    uint2 a1 = vb[(size_t)iA.y * 16 + fc];
    uint2 a2 = vb[(size_t)iA.z * 16 + fc];
    uint2 a3 = vb[(size_t)iA.w * 16 + fc];
    uint2 b0 = vb[(size_t)iB.x * 16 + fc];
    uint2 b1 = vb[(size_t)iB.y * 16 + fc];
    uint2 b2 = vb[(size_t)iB.z * 16 + fc];
    uint2 b3 = vb[(size_t)iB.w * 16 + fc];
    ACCUM(a0) ACCUM(a1) ACCUM(a2) ACCUM(a3)
    ACCUM(b0) ACCUM(b1) ACCUM(b2) ACCUM(b3)
  }
  if (p < e2) {                     // one 16-edge unit left
    int4 iA = csr4[(p >> 2) + eg];
    uint2 a0 = vb[(size_t)iA.x * 16 + fc];
    uint2 a1 = vb[(size_t)iA.y * 16 + fc];
    uint2 a2 = vb[(size_t)iA.z * 16 + fc];
    uint2 a3 = vb[(size_t)iA.w * 16 + fc];
    ACCUM(a0) ACCUM(a1) ACCUM(a2) ACCUM(a3)
  }
#undef ACCUM
  ax += __shfl_xor(ax, 16); ay += __shfl_xor(ay, 16);
  az += __shfl_xor(az, 16); aw += __shfl_xor(aw, 16);
  ax += __shfl_xor(ax, 32); ay += __shfl_xor(ay, 32);
  az += __shfl_xor(az, 32); aw += __shfl_xor(aw, 32);
  uint2 z = vb[fc];
  float pc = (float)padc;
  ax -= pc * __uint_as_float(z.x << 16);
  ay -= pc * __uint_as_float(z.x & 0xffff0000u);
  az -= pc * __uint_as_float(z.y << 16);
  aw -= pc * __uint_as_float(z.y & 0xffff0000u);
  return make_float4(ax, ay, az, aw);
}

// ---------- fused layer1+2-transform (MFMA) ----------
#define NB1 32
#define XS_S 72
#define HS_S 136
#define W1_S 72
#define W2_S 136
__global__ __launch_bounds__(512) void gmm1_k(
    const unsigned short* __restrict__ xb, const int* __restrict__ cursors,
    const int* __restrict__ csr_src, const unsigned short* __restrict__ W1t,
    const float* __restrict__ b1, const unsigned short* __restrict__ W2t,
    unsigned short* __restrict__ g) {
  __shared__ unsigned short W1l[HID * W1_S];    // 18 KB
  __shared__ unsigned short W2l[HID2 * W2_S];   // 17 KB
  __shared__ unsigned short xsb[NB1 * XS_S];    // 4.5 KB
  __shared__ unsigned short hsb[NB1 * HS_S];    // 8.5 KB
  __shared__ float b1l[HID];                    // 0.5 KB
  int t = threadIdx.x;
  {
    const uint2* s1 = (const uint2*)W1t;
    for (int i = t; i < HID * IN_F / 4; i += 512) {
      int j = i >> 4, k4 = i & 15;
      *(uint2*)&W1l[j * W1_S + k4 * 4] = s1[i];
    }
    const uint2* s2 = (const uint2*)W2t;
    for (int i = t; i < HID2 * HID / 4; i += 512) {
      int j = i >> 5, k4 = i & 31;
      *(uint2*)&W2l[j * W2_S + k4 * 4] = s2[i];
    }
    if (t < HID) b1l[t] = b1[t];
  }
  int node0 = blockIdx.x * NB1;
  int wave = t >> 6;
  int lane = t & 63;
  int eg = lane >> 4;
  int fc = lane & 15;
  {
    const uint2* xv = (const uint2*)xb;
    for (int i = 0; i < 4; i++) {
      int ln = wave * 4 + i;
      int n = node0 + ln;
      int s = n * SEG;
      int d = cursors[n] - s;
      int dp = (d + 15) & ~15;
      float4 a = gather_bf16(xv, csr_src, s, s + dp, dp - d, eg, fc);
      float inv = 1.0f / (d < 1 ? 1.0f : (float)d);
      if (eg == 0) {
        ushort4 o;
        o.x = bf_rne(a.x * inv); o.y = bf_rne(a.y * inv);
        o.z = bf_rne(a.z * inv); o.w = bf_rne(a.w * inv);
        *(ushort4*)&xsb[ln * XS_S + fc * 4] = o;
      }
    }
  }
  __syncthreads();
  int lr = lane & 15;
  int kb = lane >> 4;
  // ---- mm1 (MFMA): hsb = relu(xsb @ W1 + b1), wave w -> col-tile c=w ----
  {
    int c = wave;
#pragma unroll
    for (int m = 0; m < 2; m++) {
      f32x4 acc = {0.f, 0.f, 0.f, 0.f};
#pragma unroll
      for (int s = 0; s < 2; s++) {
        bfrag af = *(const bfrag*)&xsb[(m * 16 + lr) * XS_S + s * 32 + kb * 8];
        bfrag bf = *(const bfrag*)&W1l[(c * 16 + lr) * W1_S + s * 32 + kb * 8];
        acc = __builtin_amdgcn_mfma_f32_16x16x32_bf16(af, bf, acc, 0, 0, 0);
      }
      int col = c * 16 + lr;
      float bb = b1l[col];
#pragma unroll
      for (int q = 0; q < 4; q++) {
        int r = m * 16 + kb * 4 + q;
        float v = acc[q] + bb;
        hsb[r * HS_S + col] = bf_rne(v > 0.0f ? v : 0.0f);
      }
    }
  }
  __syncthreads();
  // ---- mm2 (MFMA): g = bf16(hsb @ W2), wave w -> (m=w>>2, c=w&3) ----
  {
    int m = wave >> 2, c = wave & 3;
    f32x4 acc = {0.f, 0.f, 0.f, 0.f};
#pragma unroll
    for (int s = 0; s < 4; s++) {
      bfrag af = *(const bfrag*)&hsb[(m * 16 + lr) * HS_S + s * 32 + kb * 8];
      bfrag bf = *(const bfrag*)&W2l[(c * 16 + lr) * W2_S + s * 32 + kb * 8];
      acc = __builtin_amdgcn_mfma_f32_16x16x32_bf16(af, bf, acc, 0, 0, 0);
    }
    int col = c * 16 + lr;
#pragma unroll
    for (int q = 0; q < 4; q++) {
      int r = m * 16 + kb * 4 + q;
      g[(size_t)(node0 + r) * HID2 + col] = bf_rne(acc[q]);
    }
  }
}

// ---------- layer 2 gather + head: out = relu(agg(g)/deg + b2) @ W3 + b3 ---
#define NBH 32
__global__ __launch_bounds__(512) void ghead_k(
    const unsigned short* __restrict__ g, const int* __restrict__ cursors,
    const int* __restrict__ csr_src, const float* __restrict__ b2,
    const float* __restrict__ W3, const float* __restrict__ b3,
    float* __restrict__ out) {
  __shared__ float W3l[HID2 * NCLS];     // 2.5 KB
  __shared__ float hs[NBH][HID2 + 4];    // 8.5 KB
  int t = threadIdx.x;
  for (int i = t; i < HID2 * NCLS; i += 512) W3l[i] = W3[i];
  int node0 = blockIdx.x * NBH;
  int lane = t & 63;
  int wave = t >> 6;
  int eg = lane >> 4;
  int fc = lane & 15;
  const uint2* gv = (const uint2*)g;
  const float4* b2f4 = (const float4*)b2;
  for (int i = 0; i < 4; i++) {
    int ln = wave * 4 + i;
    int n = node0 + ln;
    int s = n * SEG;
    int d = cursors[n] - s;
    int dp = (d + 15) & ~15;
    float4 a = gather_bf16(gv, csr_src, s, s + dp, dp - d, eg, fc);
    float inv = 1.0f / (d < 1 ? 1.0f : (float)d);
    if (eg == 0) {
      float4 bb = b2f4[fc];
      float4 v;
      v.x = a.x * inv + bb.x; v.y = a.y * inv + bb.y;
      v.z = a.z * inv + bb.z; v.w = a.w * inv + bb.w;
      v.x = v.x > 0.0f ? v.x : 0.0f;
      v.y = v.y > 0.0f ? v.y : 0.0f;
      v.z = v.z > 0.0f ? v.z : 0.0f;
      v.w = v.w > 0.0f ? v.w : 0.0f;
      *(float4*)&hs[ln][fc * 4] = v;
    }
  }
  __syncthreads();
  if (t < NBH * NCLS) {
    int n = t / NCLS;
    int c = t - n * NCLS;
    float a = b3[c];
    for (int k = 0; k < HID2; k++) a += hs[n][k] * W3l[k * NCLS + c];
    out[(size_t)(node0 + n) * NCLS + c] = a;
  }
}

extern "C" void kernel_launch(void* const* d_in, const int* in_sizes, int n_in,
                              void* d_out, int out_size, void* d_ws, size_t ws_size,
                              hipStream_t stream) {
  const float* x  = (const float*)d_in[0];
  const int*   ei = (const int*)d_in[1];
  const int*   row = ei;
  const int*   col = ei + N_EDGES;
  const float* W1 = (const float*)d_in[3];
  const float* b1 = (const float*)d_in[4];
  const float* W2 = (const float*)d_in[5];
  const float* b2 = (const float*)d_in[6];
  const float* W3 = (const float*)d_in[7];
  const float* b3 = (const float*)d_in[8];
  float* out = (float*)d_out;

  char* ws = (char*)d_ws;
  int*            cursors = (int*)ws;                            // 400 KB
  int*            bcnt    = (int*)(ws + (512 << 10));            // 32 B
  unsigned short* W1t     = (unsigned short*)(ws + (520 << 10)); // 16 KB
  unsigned short* W2t     = (unsigned short*)(ws + (552 << 10)); // 16 KB
  int*            csr_src = (int*)(ws + (1 << 20));              // 25.6 MB
  int2*           pairs   = (int2*)(ws + (28 << 20));            // 13.4 MB
  unsigned short* xb      = (unsigned short*)(ws + (42 << 20));  // 12.8 MB
  unsigned short* g       = (unsigned short*)(ws + (56 << 20));  // 12.8 MB

  // ---- prep: bf16 cast + W transpose + binned fixed-stride CSR build ----
  hipMemsetAsync(csr_src, 0, (size_t)N_NODES * SEG * sizeof(int), stream);
  hipMemsetAsync(bcnt, 0, NRANGE * sizeof(int), stream);
  curs_init_k<<<(N_NODES + 255) / 256, 256, 0, stream>>>(cursors);
  wtrans_k<<<(IN_F * HID + HID * HID2) / 256, 256, 0, stream>>>(W1, W2, W1t, W2t);
  cast_k<<<N_NODES * IN_F / 8 / 256, 256, 0, stream>>>(x, xb);
  binA_k<<<N_EDGES / EBA, 256, 0, stream>>>(row, col, bcnt, pairs);
  binB_k<<<NRANGE * 64, 256, 0, stream>>>(pairs, bcnt, cursors, csr_src);

  // ---- fused layer 1 + transform: gather -> MFMA mm1 -> MFMA mm2 -> g ----
  gmm1_k<<<N_NODES / NB1, 512, 0, stream>>>(xb, cursors, csr_src, W1t, b1, W2t, g);

  // ---- layer 2 gather + head ----
  ghead_k<<<N_NODES / NBH, 512, 0, stream>>>(g, cursors, csr_src, b2, W3, b3, out);
}

// Round 11
// 149.474 us; speedup vs baseline: 1.3420x; 1.3420x over previous
//
#include <hip/hip_runtime.h>

#define N_NODES 100000
#define N_EDGES 1600000
#define IN_F 64
#define HID 128
#define HID2 64
#define NCLS 10

// fixed-stride padded CSR: 64 slots per node (max Poisson-16 degree ~45)
#define SEG 64

// two-level binning: 128 sub-buckets of 782 nodes (200KB csr window each)
#define NBUCK 128
#define SUBR 782                       // ceil(100000/128)
#define CAP2 14000                     // mean 12512, 13 sigma margin
#define EBA 6250                       // edges per binA block (256 blocks)

typedef __attribute__((ext_vector_type(8))) short bfrag;
typedef __attribute__((ext_vector_type(4))) float f32x4;

// ---- RNE float->bf16 ----
__device__ __forceinline__ unsigned short bf_rne(float f) {
  unsigned int u = __float_as_uint(f);
  u += 0x7fffu + ((u >> 16) & 1u);
  return (unsigned short)(u >> 16);
}

// ---------------- cast x -> bf16 (8 floats / thread) ----------------
__global__ __launch_bounds__(256) void cast_k(const float* __restrict__ x,
                                              unsigned short* __restrict__ xb) {
  int i = blockIdx.x * blockDim.x + threadIdx.x;   // 8-float unit
  const float4* xf4 = (const float4*)x;
  float4 a = xf4[2 * i];
  float4 b = xf4[2 * i + 1];
  ushort4 o0, o1;
  o0.x = bf_rne(a.x); o0.y = bf_rne(a.y); o0.z = bf_rne(a.z); o0.w = bf_rne(a.w);
  o1.x = bf_rne(b.x); o1.y = bf_rne(b.y); o1.z = bf_rne(b.z); o1.w = bf_rne(b.w);
  ushort4* ob = (ushort4*)xb;
  ob[2 * i] = o0;
  ob[2 * i + 1] = o1;
}

// ---------------- W1/W2 -> bf16 transposed [out][k] (once) ----------------
__global__ __launch_bounds__(256) void wtrans_k(const float* __restrict__ W1,
                                                const float* __restrict__ W2,
                                                unsigned short* __restrict__ W1t,
                                                unsigned short* __restrict__ W2t) {
  int i = blockIdx.x * 256 + threadIdx.x;          // 0 .. 16383
  if (i < IN_F * HID) {                            // W1t[j][k] = W1[k][j]
    int j = i >> 6, k = i & 63;                    // j<128, k<64
    W1t[i] = bf_rne(W1[k * HID + j]);
  } else {
    int i2 = i - IN_F * HID;                       // W2t[j][k] = W2[k][j]
    int j = i2 >> 7, k = i2 & 127;                 // j<64, k<128
    W2t[i2] = bf_rne(W2[k * HID2 + j]);
  }
}

// ---- binA: bin edges into 128 node-range buckets as (dst,src) pairs ----
// Block-aggregated cursors: LDS histogram -> 128 global atomics/block ->
// dense per-block bucket chunks (no line amplification).
__global__ __launch_bounds__(256) void binA_k(const int* __restrict__ row,
                                              const int* __restrict__ col,
                                              int* __restrict__ bcnt,
                                              int2* __restrict__ pairs) {
  __shared__ int hcnt[NBUCK];
  __shared__ int hbase[NBUCK];
  int t = threadIdx.x;
  if (t < NBUCK) hcnt[t] = 0;
  __syncthreads();
  int e0 = blockIdx.x * EBA;
  int e1 = e0 + EBA;
  for (int e = e0 + t; e < e1; e += 256) {
    int b = col[e] / SUBR;
    atomicAdd(&hcnt[b], 1);
  }
  __syncthreads();
  if (t < NBUCK) {
    hbase[t] = atomicAdd(&bcnt[t], hcnt[t]);
    hcnt[t] = 0;
  }
  __syncthreads();
  for (int e = e0 + t; e < e1; e += 256) {
    int dst = col[e];
    int src = row[e];
    int b = dst / SUBR;
    int pos = hbase[b] + atomicAdd(&hcnt[b], 1);
    pairs[(size_t)b * CAP2 + pos] = make_int2(dst, src);
  }
}

// ---- binB: one block per bucket; LDS cursors; 200KB private csr window ----
// Dirty window per block = 200KB << 4MB L2 -> every line fully assembled
// before eviction. Also writes final cursors[] and zeroes pad slots, so no
// 25.6MB csr memset is needed.
__global__ __launch_bounds__(512) void binB_k(const int2* __restrict__ pairs,
                                              const int* __restrict__ bcnt,
                                              int* __restrict__ cursors,
                                              int* __restrict__ csr_src) {
  __shared__ int cur[SUBR];
  int b = blockIdx.x;
  int t = threadIdx.x;
  int lo = b * SUBR;
  for (int i = t; i < SUBR; i += 512) cur[i] = 0;
  __syncthreads();
  int cnt = bcnt[b];
  const int2* bp = pairs + (size_t)b * CAP2;
  for (int i = t; i < cnt; i += 512) {
    int2 p = bp[i];
    int pos = atomicAdd(&cur[p.x - lo], 1);
    csr_src[(size_t)p.x * SEG + pos] = p.y;
  }
  __syncthreads();
  // publish cursors (degree) + zero the pad slots up to the next 16-mult
  for (int i = t; i < SUBR; i += 512) {
    int n = lo + i;
    if (n < N_NODES) {
      int d = cur[i];
      cursors[n] = n * SEG + d;
      int dp = (d + 15) & ~15;
      for (int q = d; q < dp; q++) csr_src[(size_t)n * SEG + q] = 0;
    }
  }
}

// ---------- bf16 padded gather: rows of 64 bf16 = 128 B = 16 uint2 chunks --
__device__ __forceinline__ float4 gather_bf16(const uint2* __restrict__ vb,
                                              const int* __restrict__ csr,
                                              int s, int e2, int padc,
                                              int eg, int fc) {
  float ax = 0.f, ay = 0.f, az = 0.f, aw = 0.f;
  const int4* csr4 = (const int4*)csr;
#define ACCUM(w)                                                    \
  {                                                                 \
    ax += __uint_as_float((w).x << 16);                             \
    ay += __uint_as_float((w).x & 0xffff0000u);                     \
    az += __uint_as_float((w).y << 16);                             \
    aw += __uint_as_float((w).y & 0xffff0000u);                     \
  }
  int p = s;
  for (; p + 32 <= e2; p += 32) {   // 2 units: 8 gathers in flight
    int4 iA = csr4[(p >> 2) + eg];
    int4 iB = csr4[((p + 16) >> 2) + eg];
    uint2 a0 = vb[(size_t)iA.x * 16 + fc];
    uint2 a1 = vb[(size_t)iA.y * 16 + fc];
    uint2 a2 = vb[(size_t)iA.z * 16 + fc];
    uint2 a3 = vb[(size_t)iA.w * 16 + fc];
    uint2 b0 = vb[(size_t)iB.x * 16 + fc];
    uint2 b1 = vb[(size_t)iB.y * 16 + fc];
    uint2 b2 = vb[(size_t)iB.z * 16 + fc];
    uint2 b3 = vb[(size_t)iB.w * 16 + fc];
    ACCUM(a0) ACCUM(a1) ACCUM(a2) ACCUM(a3)
    ACCUM(b0) ACCUM(b1) ACCUM(b2) ACCUM(b3)
  }
  if (p < e2) {                     // one 16-edge unit left
    int4 iA = csr4[(p >> 2) + eg];
    uint2 a0 = vb[(size_t)iA.x * 16 + fc];
    uint2 a1 = vb[(size_t)iA.y * 16 + fc];
    uint2 a2 = vb[(size_t)iA.z * 16 + fc];
    uint2 a3 = vb[(size_t)iA.w * 16 + fc];
    ACCUM(a0) ACCUM(a1) ACCUM(a2) ACCUM(a3)
  }
#undef ACCUM
  ax += __shfl_xor(ax, 16); ay += __shfl_xor(ay, 16);
  az += __shfl_xor(az, 16); aw += __shfl_xor(aw, 16);
  ax += __shfl_xor(ax, 32); ay += __shfl_xor(ay, 32);
  az += __shfl_xor(az, 32); aw += __shfl_xor(aw, 32);
  uint2 z = vb[fc];
  float pc = (float)padc;
  ax -= pc * __uint_as_float(z.x << 16);
  ay -= pc * __uint_as_float(z.x & 0xffff0000u);
  az -= pc * __uint_as_float(z.y << 16);
  aw -= pc * __uint_as_float(z.y & 0xffff0000u);
  return make_float4(ax, ay, az, aw);
}

// ---------- fused layer1+2-transform (MFMA) ----------
#define NB1 32
#define XS_S 72
#define HS_S 136
#define W1_S 72
#define W2_S 136
__global__ __launch_bounds__(512) void gmm1_k(
    const unsigned short* __restrict__ xb, const int* __restrict__ cursors,
    const int* __restrict__ csr_src, const unsigned short* __restrict__ W1t,
    const float* __restrict__ b1, const unsigned short* __restrict__ W2t,
    unsigned short* __restrict__ g) {
  __shared__ unsigned short W1l[HID * W1_S];    // 18 KB
  __shared__ unsigned short W2l[HID2 * W2_S];   // 17 KB
  __shared__ unsigned short xsb[NB1 * XS_S];    // 4.5 KB
  __shared__ unsigned short hsb[NB1 * HS_S];    // 8.5 KB
  __shared__ float b1l[HID];                    // 0.5 KB
  int t = threadIdx.x;
  {
    const uint2* s1 = (const uint2*)W1t;
    for (int i = t; i < HID * IN_F / 4; i += 512) {
      int j = i >> 4, k4 = i & 15;
      *(uint2*)&W1l[j * W1_S + k4 * 4] = s1[i];
    }
    const uint2* s2 = (const uint2*)W2t;
    for (int i = t; i < HID2 * HID / 4; i += 512) {
      int j = i >> 5, k4 = i & 31;
      *(uint2*)&W2l[j * W2_S + k4 * 4] = s2[i];
    }
    if (t < HID) b1l[t] = b1[t];
  }
  int node0 = blockIdx.x * NB1;
  int wave = t >> 6;
  int lane = t & 63;
  int eg = lane >> 4;
  int fc = lane & 15;
  {
    const uint2* xv = (const uint2*)xb;
    for (int i = 0; i < 4; i++) {
      int ln = wave * 4 + i;
      int n = node0 + ln;
      int s = n * SEG;
      int d = cursors[n] - s;
      int dp = (d + 15) & ~15;
      float4 a = gather_bf16(xv, csr_src, s, s + dp, dp - d, eg, fc);
      float inv = 1.0f / (d < 1 ? 1.0f : (float)d);
      if (eg == 0) {
        ushort4 o;
        o.x = bf_rne(a.x * inv); o.y = bf_rne(a.y * inv);
        o.z = bf_rne(a.z * inv); o.w = bf_rne(a.w * inv);
        *(ushort4*)&xsb[ln * XS_S + fc * 4] = o;
      }
    }
  }
  __syncthreads();
  int lr = lane & 15;
  int kb = lane >> 4;
  // ---- mm1 (MFMA): hsb = relu(xsb @ W1 + b1), wave w -> col-tile c=w ----
  {
    int c = wave;
#pragma unroll
    for (int m = 0; m < 2; m++) {
      f32x4 acc = {0.f, 0.f, 0.f, 0.f};
#pragma unroll
      for (int s = 0; s < 2; s++) {
        bfrag af = *(const bfrag*)&xsb[(m * 16 + lr) * XS_S + s * 32 + kb * 8];
        bfrag bf = *(const bfrag*)&W1l[(c * 16 + lr) * W1_S + s * 32 + kb * 8];
        acc = __builtin_amdgcn_mfma_f32_16x16x32_bf16(af, bf, acc, 0, 0, 0);
      }
      int col = c * 16 + lr;
      float bb = b1l[col];
#pragma unroll
      for (int q = 0; q < 4; q++) {
        int r = m * 16 + kb * 4 + q;
        float v = acc[q] + bb;
        hsb[r * HS_S + col] = bf_rne(v > 0.0f ? v : 0.0f);
      }
    }
  }
  __syncthreads();
  // ---- mm2 (MFMA): g = bf16(hsb @ W2), wave w -> (m=w>>2, c=w&3) ----
  {
    int m = wave >> 2, c = wave & 3;
    f32x4 acc = {0.f, 0.f, 0.f, 0.f};
#pragma unroll
    for (int s = 0; s < 4; s++) {
      bfrag af = *(const bfrag*)&hsb[(m * 16 + lr) * HS_S + s * 32 + kb * 8];
      bfrag bf = *(const bfrag*)&W2l[(c * 16 + lr) * W2_S + s * 32 + kb * 8];
      acc = __builtin_amdgcn_mfma_f32_16x16x32_bf16(af, bf, acc, 0, 0, 0);
    }
    int col = c * 16 + lr;
#pragma unroll
    for (int q = 0; q < 4; q++) {
      int r = m * 16 + kb * 4 + q;
      g[(size_t)(node0 + r) * HID2 + col] = bf_rne(acc[q]);
    }
  }
}

// ---------- layer 2 gather + head: out = relu(agg(g)/deg + b2) @ W3 + b3 ---
#define NBH 32
__global__ __launch_bounds__(512) void ghead_k(
    const unsigned short* __restrict__ g, const int* __restrict__ cursors,
    const int* __restrict__ csr_src, const float* __restrict__ b2,
    const float* __restrict__ W3, const float* __restrict__ b3,
    float* __restrict__ out) {
  __shared__ float W3l[HID2 * NCLS];     // 2.5 KB
  __shared__ float hs[NBH][HID2 + 4];    // 8.5 KB
  int t = threadIdx.x;
  for (int i = t; i < HID2 * NCLS; i += 512) W3l[i] = W3[i];
  int node0 = blockIdx.x * NBH;
  int lane = t & 63;
  int wave = t >> 6;
  int eg = lane >> 4;
  int fc = lane & 15;
  const uint2* gv = (const uint2*)g;
  const float4* b2f4 = (const float4*)b2;
  for (int i = 0; i < 4; i++) {
    int ln = wave * 4 + i;
    int n = node0 + ln;
    int s = n * SEG;
    int d = cursors[n] - s;
    int dp = (d + 15) & ~15;
    float4 a = gather_bf16(gv, csr_src, s, s + dp, dp - d, eg, fc);
    float inv = 1.0f / (d < 1 ? 1.0f : (float)d);
    if (eg == 0) {
      float4 bb = b2f4[fc];
      float4 v;
      v.x = a.x * inv + bb.x; v.y = a.y * inv + bb.y;
      v.z = a.z * inv + bb.z; v.w = a.w * inv + bb.w;
      v.x = v.x > 0.0f ? v.x : 0.0f;
      v.y = v.y > 0.0f ? v.y : 0.0f;
      v.z = v.z > 0.0f ? v.z : 0.0f;
      v.w = v.w > 0.0f ? v.w : 0.0f;
      *(float4*)&hs[ln][fc * 4] = v;
    }
  }
  __syncthreads();
  if (t < NBH * NCLS) {
    int n = t / NCLS;
    int c = t - n * NCLS;
    float a = b3[c];
    for (int k = 0; k < HID2; k++) a += hs[n][k] * W3l[k * NCLS + c];
    out[(size_t)(node0 + n) * NCLS + c] = a;
  }
}

extern "C" void kernel_launch(void* const* d_in, const int* in_sizes, int n_in,
                              void* d_out, int out_size, void* d_ws, size_t ws_size,
                              hipStream_t stream) {
  const float* x  = (const float*)d_in[0];
  const int*   ei = (const int*)d_in[1];
  const int*   row = ei;
  const int*   col = ei + N_EDGES;
  const float* W1 = (const float*)d_in[3];
  const float* b1 = (const float*)d_in[4];
  const float* W2 = (const float*)d_in[5];
  const float* b2 = (const float*)d_in[6];
  const float* W3 = (const float*)d_in[7];
  const float* b3 = (const float*)d_in[8];
  float* out = (float*)d_out;

  char* ws = (char*)d_ws;
  int*            cursors = (int*)ws;                            // 400 KB
  int*            bcnt    = (int*)(ws + (512 << 10));            // 512 B
  unsigned short* W1t     = (unsigned short*)(ws + (520 << 10)); // 16 KB
  unsigned short* W2t     = (unsigned short*)(ws + (552 << 10)); // 16 KB
  int*            csr_src = (int*)(ws + (1 << 20));              // 25.6 MB
  int2*           pairs   = (int2*)(ws + (28 << 20));            // 14.3 MB
  unsigned short* xb      = (unsigned short*)(ws + (43 << 20));  // 12.8 MB
  unsigned short* g       = (unsigned short*)(ws + (57 << 20));  // 12.8 MB

  // ---- prep: bf16 cast + W transpose + two-level binned CSR build ----
  hipMemsetAsync(bcnt, 0, NBUCK * sizeof(int), stream);
  wtrans_k<<<(IN_F * HID + HID * HID2) / 256, 256, 0, stream>>>(W1, W2, W1t, W2t);
  cast_k<<<N_NODES * IN_F / 8 / 256, 256, 0, stream>>>(x, xb);
  binA_k<<<N_EDGES / EBA, 256, 0, stream>>>(row, col, bcnt, pairs);
  binB_k<<<NBUCK, 512, 0, stream>>>(pairs, bcnt, cursors, csr_src);

  // ---- fused layer 1 + transform: gather -> MFMA mm1 -> MFMA mm2 -> g ----
  gmm1_k<<<N_NODES / NB1, 512, 0, stream>>>(xb, cursors, csr_src, W1t, b1, W2t, g);

  // ---- layer 2 gather + head ----
  ghead_k<<<N_NODES / NBH, 512, 0, stream>>>(g, cursors, csr_src, b2, W3, b3, out);
}

// Round 12
// 148.260 us; speedup vs baseline: 1.3530x; 1.0082x over previous
//
#include <hip/hip_runtime.h>

#define N_NODES 100000
#define N_EDGES 1600000
#define IN_F 64
#define HID 128
#define HID2 64
#define NCLS 10

// fixed-stride padded CSR: 64 slots per node (max Poisson-16 degree ~45)
#define SEG 64

// two-level binning: 128 sub-buckets of 782 nodes (200KB csr window each)
#define NBUCK 128
#define SUBR 782                       // ceil(100000/128)
#define CAP2 14000                     // mean 12512, 13 sigma margin
#define EBA 6250                       // edges per binA block (256 blocks)

typedef __attribute__((ext_vector_type(8))) short bfrag;
typedef __attribute__((ext_vector_type(4))) float f32x4;

// ---- RNE float->bf16 ----
__device__ __forceinline__ unsigned short bf_rne(float f) {
  unsigned int u = __float_as_uint(f);
  u += 0x7fffu + ((u >> 16) & 1u);
  return (unsigned short)(u >> 16);
}

// ---------------- cast x -> bf16 (8 floats / thread) ----------------
__global__ __launch_bounds__(256) void cast_k(const float* __restrict__ x,
                                              unsigned short* __restrict__ xb) {
  int i = blockIdx.x * blockDim.x + threadIdx.x;   // 8-float unit
  const float4* xf4 = (const float4*)x;
  float4 a = xf4[2 * i];
  float4 b = xf4[2 * i + 1];
  ushort4 o0, o1;
  o0.x = bf_rne(a.x); o0.y = bf_rne(a.y); o0.z = bf_rne(a.z); o0.w = bf_rne(a.w);
  o1.x = bf_rne(b.x); o1.y = bf_rne(b.y); o1.z = bf_rne(b.z); o1.w = bf_rne(b.w);
  ushort4* ob = (ushort4*)xb;
  ob[2 * i] = o0;
  ob[2 * i + 1] = o1;
}

// ---------------- W1/W2 -> bf16 transposed [out][k] (once) ----------------
__global__ __launch_bounds__(256) void wtrans_k(const float* __restrict__ W1,
                                                const float* __restrict__ W2,
                                                unsigned short* __restrict__ W1t,
                                                unsigned short* __restrict__ W2t) {
  int i = blockIdx.x * 256 + threadIdx.x;          // 0 .. 16383
  if (i < IN_F * HID) {                            // W1t[j][k] = W1[k][j]
    int j = i >> 6, k = i & 63;                    // j<128, k<64
    W1t[i] = bf_rne(W1[k * HID + j]);
  } else {
    int i2 = i - IN_F * HID;                       // W2t[j][k] = W2[k][j]
    int j = i2 >> 7, k = i2 & 127;                 // j<64, k<128
    W2t[i2] = bf_rne(W2[k * HID2 + j]);
  }
}

// ---- binA: bin edges into 128 buckets as packed (local<<17|src) u32 ----
__global__ __launch_bounds__(256) void binA_k(const int* __restrict__ row,
                                              const int* __restrict__ col,
                                              int* __restrict__ bcnt,
                                              unsigned int* __restrict__ pairs) {
  __shared__ int hcnt[NBUCK];
  __shared__ int hbase[NBUCK];
  int t = threadIdx.x;
  if (t < NBUCK) hcnt[t] = 0;
  __syncthreads();
  int e0 = blockIdx.x * EBA;
  int e1 = e0 + EBA;
  for (int e = e0 + t; e < e1; e += 256) {
    int b = col[e] / SUBR;
    atomicAdd(&hcnt[b], 1);
  }
  __syncthreads();
  if (t < NBUCK) {
    hbase[t] = atomicAdd(&bcnt[t], hcnt[t]);
    hcnt[t] = 0;
  }
  __syncthreads();
  for (int e = e0 + t; e < e1; e += 256) {
    int dst = col[e];
    int src = row[e];
    int b = dst / SUBR;
    int pos = hbase[b] + atomicAdd(&hcnt[b], 1);
    pairs[(size_t)b * CAP2 + pos] =
        ((unsigned)(dst - b * SUBR) << 17) | (unsigned)src;
  }
}

// ---- binB: one block per bucket; LDS cursors; 200KB private csr window ----
// Zero-fills slots d..cons (cons = 32 or ceil16(d)) so the gather can read
// the first 32 slots (and any tail units) unconditionally.
__global__ __launch_bounds__(512) void binB_k(const unsigned int* __restrict__ pairs,
                                              const int* __restrict__ bcnt,
                                              int* __restrict__ cursors,
                                              int* __restrict__ csr_src) {
  __shared__ int cur[SUBR];
  int b = blockIdx.x;
  int t = threadIdx.x;
  int lo = b * SUBR;
  for (int i = t; i < SUBR; i += 512) cur[i] = 0;
  __syncthreads();
  int cnt = bcnt[b];
  const unsigned int* bp = pairs + (size_t)b * CAP2;
  for (int i = t; i < cnt; i += 512) {
    unsigned w = bp[i];
    int local = w >> 17;
    int src = (int)(w & 0x1ffffu);
    int pos = atomicAdd(&cur[local], 1);
    if (pos < SEG) csr_src[(size_t)(lo + local) * SEG + pos] = src;
  }
  __syncthreads();
  for (int i = t; i < SUBR; i += 512) {
    int n = lo + i;
    if (n < N_NODES) {
      int d = cur[i];
      if (d > SEG) d = SEG;
      cursors[n] = n * SEG + d;
      int cons = d <= 32 ? 32 : ((d + 15) & ~15);
      for (int q = d; q < cons; q++) csr_src[(size_t)n * SEG + q] = 0;
    }
  }
}

// ---------- pipelined 4-node bf16 gather ----------
// Wave handles nodes n0..n0+3. All idx loads (8 int4) issue first (addresses
// independent of degree), then 3 nodes' row loads (24 uint2) are in flight
// before the first accumulate. Slots [0,32) are always initialized (binB),
// pad slots hold src=0 -> row0, subtracted via padc*row0 after the reduce.
#define ACC1(r)                                                     \
  {                                                                 \
    ax += __uint_as_float((r).x << 16);                             \
    ay += __uint_as_float((r).x & 0xffff0000u);                     \
    az += __uint_as_float((r).y << 16);                             \
    aw += __uint_as_float((r).y & 0xffff0000u);                     \
  }
#define LD8(r, ia, ib)                                              \
  {                                                                 \
    r[0] = vb[(size_t)(unsigned)(ia).x * 16 + fc];                  \
    r[1] = vb[(size_t)(unsigned)(ia).y * 16 + fc];                  \
    r[2] = vb[(size_t)(unsigned)(ia).z * 16 + fc];                  \
    r[3] = vb[(size_t)(unsigned)(ia).w * 16 + fc];                  \
    r[4] = vb[(size_t)(unsigned)(ib).x * 16 + fc];                  \
    r[5] = vb[(size_t)(unsigned)(ib).y * 16 + fc];                  \
    r[6] = vb[(size_t)(unsigned)(ib).z * 16 + fc];                  \
    r[7] = vb[(size_t)(unsigned)(ib).w * 16 + fc];                  \
  }
#define NODE_BODY(i, rbuf, dd, EXTRA)                               \
  {                                                                 \
    float ax = 0.f, ay = 0.f, az = 0.f, aw = 0.f;                   \
    ACC1(rbuf[0]) ACC1(rbuf[1]) ACC1(rbuf[2]) ACC1(rbuf[3])         \
    ACC1(rbuf[4]) ACC1(rbuf[5]) ACC1(rbuf[6]) ACC1(rbuf[7])         \
    int cons = 32;                                                  \
    if (dd > 32) {                                                  \
      cons = (dd + 15) & ~15;                                       \
      int sbase = (n0 + i) * SEG;                                   \
      for (int p = sbase + 32; p < sbase + cons; p += 16) {         \
        int4 iT = csr4[(p >> 2) + eg];                              \
        uint2 t0 = vb[(size_t)(unsigned)iT.x * 16 + fc];            \
        uint2 t1 = vb[(size_t)(unsigned)iT.y * 16 + fc];            \
        uint2 t2 = vb[(size_t)(unsigned)iT.z * 16 + fc];            \
        uint2 t3 = vb[(size_t)(unsigned)iT.w * 16 + fc];            \
        ACC1(t0) ACC1(t1) ACC1(t2) ACC1(t3)                         \
      }                                                             \
    }                                                               \
    EXTRA                                                           \
    ax += __shfl_xor(ax, 16); ay += __shfl_xor(ay, 16);             \
    az += __shfl_xor(az, 16); aw += __shfl_xor(aw, 16);             \
    ax += __shfl_xor(ax, 32); ay += __shfl_xor(ay, 32);             \
    az += __shfl_xor(az, 32); aw += __shfl_xor(aw, 32);             \
    float pc = (float)(cons - dd);                                  \
    res[i] = make_float4(ax - pc * zx, ay - pc * zy,                \
                         az - pc * zz, aw - pc * zw);               \
    inv[i] = 1.0f / (dd < 1 ? 1.0f : (float)(dd));                  \
  }

__device__ __forceinline__ void gather4_bf16(
    const uint2* __restrict__ vb, const int* __restrict__ csr,
    const int* __restrict__ cursors, int n0, int eg, int fc,
    float4 res[4], float inv[4]) {
  const int4* csr4 = (const int4*)csr;
  size_t rb = (size_t)n0 * 16;               // 16 int4 per SEG
  int4 iA0 = csr4[rb + eg],      iB0 = csr4[rb + 4 + eg];
  int4 iA1 = csr4[rb + 16 + eg], iB1 = csr4[rb + 20 + eg];
  int4 iA2 = csr4[rb + 32 + eg], iB2 = csr4[rb + 36 + eg];
  int4 iA3 = csr4[rb + 48 + eg], iB3 = csr4[rb + 52 + eg];
  int d0 = cursors[n0 + 0] - (n0 + 0) * SEG;
  int d1 = cursors[n0 + 1] - (n0 + 1) * SEG;
  int d2 = cursors[n0 + 2] - (n0 + 2) * SEG;
  int d3 = cursors[n0 + 3] - (n0 + 3) * SEG;
  uint2 rA[8], rB[8], rC[8];
  LD8(rA, iA0, iB0)
  LD8(rB, iA1, iB1)
  LD8(rC, iA2, iB2)
  uint2 z = vb[fc];
  float zx = __uint_as_float(z.x << 16);
  float zy = __uint_as_float(z.x & 0xffff0000u);
  float zz = __uint_as_float(z.y << 16);
  float zw = __uint_as_float(z.y & 0xffff0000u);
  NODE_BODY(0, rA, d0, LD8(rA, iA3, iB3))
  NODE_BODY(1, rB, d1, )
  NODE_BODY(2, rC, d2, )
  NODE_BODY(3, rA, d3, )
}

// ---------- fused layer1+2-transform (MFMA) ----------
#define NB1 32
#define XS_S 72
#define HS_S 136
#define W1_S 72
#define W2_S 136
__global__ __launch_bounds__(512, 4) void gmm1_k(
    const unsigned short* __restrict__ xb, const int* __restrict__ cursors,
    const int* __restrict__ csr_src, const unsigned short* __restrict__ W1t,
    const float* __restrict__ b1, const unsigned short* __restrict__ W2t,
    unsigned short* __restrict__ g) {
  __shared__ unsigned short W1l[HID * W1_S];    // 18 KB
  __shared__ unsigned short W2l[HID2 * W2_S];   // 17 KB
  __shared__ unsigned short xsb[NB1 * XS_S];    // 4.5 KB
  __shared__ unsigned short hsb[NB1 * HS_S];    // 8.5 KB
  __shared__ float b1l[HID];                    // 0.5 KB
  int t = threadIdx.x;
  {
    const uint2* s1 = (const uint2*)W1t;
    for (int i = t; i < HID * IN_F / 4; i += 512) {
      int j = i >> 4, k4 = i & 15;
      *(uint2*)&W1l[j * W1_S + k4 * 4] = s1[i];
    }
    const uint2* s2 = (const uint2*)W2t;
    for (int i = t; i < HID2 * HID / 4; i += 512) {
      int j = i >> 5, k4 = i & 31;
      *(uint2*)&W2l[j * W2_S + k4 * 4] = s2[i];
    }
    if (t < HID) b1l[t] = b1[t];
  }
  int node0 = blockIdx.x * NB1;
  int wave = t >> 6;
  int lane = t & 63;
  int eg = lane >> 4;
  int fc = lane & 15;
  {
    const uint2* vb = (const uint2*)xb;
    float4 res[4];
    float inv[4];
    gather4_bf16(vb, csr_src, cursors, node0 + wave * 4, eg, fc, res, inv);
    if (eg == 0) {
#pragma unroll
      for (int i = 0; i < 4; i++) {
        ushort4 o;
        o.x = bf_rne(res[i].x * inv[i]); o.y = bf_rne(res[i].y * inv[i]);
        o.z = bf_rne(res[i].z * inv[i]); o.w = bf_rne(res[i].w * inv[i]);
        *(ushort4*)&xsb[(wave * 4 + i) * XS_S + fc * 4] = o;
      }
    }
  }
  __syncthreads();
  int lr = lane & 15;
  int kb = lane >> 4;
  // ---- mm1 (MFMA): hsb = relu(xsb @ W1 + b1), wave w -> col-tile c=w ----
  {
    int c = wave;
#pragma unroll
    for (int m = 0; m < 2; m++) {
      f32x4 acc = {0.f, 0.f, 0.f, 0.f};
#pragma unroll
      for (int s = 0; s < 2; s++) {
        bfrag af = *(const bfrag*)&xsb[(m * 16 + lr) * XS_S + s * 32 + kb * 8];
        bfrag bf = *(const bfrag*)&W1l[(c * 16 + lr) * W1_S + s * 32 + kb * 8];
        acc = __builtin_amdgcn_mfma_f32_16x16x32_bf16(af, bf, acc, 0, 0, 0);
      }
      int col = c * 16 + lr;
      float bb = b1l[col];
#pragma unroll
      for (int q = 0; q < 4; q++) {
        int r = m * 16 + kb * 4 + q;
        float v = acc[q] + bb;
        hsb[r * HS_S + col] = bf_rne(v > 0.0f ? v : 0.0f);
      }
    }
  }
  __syncthreads();
  // ---- mm2 (MFMA): g = bf16(hsb @ W2), wave w -> (m=w>>2, c=w&3) ----
  {
    int m = wave >> 2, c = wave & 3;
    f32x4 acc = {0.f, 0.f, 0.f, 0.f};
#pragma unroll
    for (int s = 0; s < 4; s++) {
      bfrag af = *(const bfrag*)&hsb[(m * 16 + lr) * HS_S + s * 32 + kb * 8];
      bfrag bf = *(const bfrag*)&W2l[(c * 16 + lr) * W2_S + s * 32 + kb * 8];
      acc = __builtin_amdgcn_mfma_f32_16x16x32_bf16(af, bf, acc, 0, 0, 0);
    }
    int col = c * 16 + lr;
#pragma unroll
    for (int q = 0; q < 4; q++) {
      int r = m * 16 + kb * 4 + q;
      g[(size_t)(node0 + r) * HID2 + col] = bf_rne(acc[q]);
    }
  }
}

// ---------- layer 2 gather + head: out = relu(agg(g)/deg + b2) @ W3 + b3 ---
#define NBH 32
__global__ __launch_bounds__(512, 4) void ghead_k(
    const unsigned short* __restrict__ g, const int* __restrict__ cursors,
    const int* __restrict__ csr_src, const float* __restrict__ b2,
    const float* __restrict__ W3, const float* __restrict__ b3,
    float* __restrict__ out) {
  __shared__ float W3l[HID2 * NCLS];     // 2.5 KB
  __shared__ float hs[NBH][HID2 + 4];    // 8.5 KB
  int t = threadIdx.x;
  for (int i = t; i < HID2 * NCLS; i += 512) W3l[i] = W3[i];
  int node0 = blockIdx.x * NBH;
  int lane = t & 63;
  int wave = t >> 6;
  int eg = lane >> 4;
  int fc = lane & 15;
  {
    const uint2* vb = (const uint2*)g;
    const float4* b2f4 = (const float4*)b2;
    float4 res[4];
    float inv[4];
    gather4_bf16(vb, csr_src, cursors, node0 + wave * 4, eg, fc, res, inv);
    if (eg == 0) {
      float4 bb = b2f4[fc];
#pragma unroll
      for (int i = 0; i < 4; i++) {
        float4 v;
        v.x = res[i].x * inv[i] + bb.x; v.y = res[i].y * inv[i] + bb.y;
        v.z = res[i].z * inv[i] + bb.z; v.w = res[i].w * inv[i] + bb.w;
        v.x = v.x > 0.0f ? v.x : 0.0f;
        v.y = v.y > 0.0f ? v.y : 0.0f;
        v.z = v.z > 0.0f ? v.z : 0.0f;
        v.w = v.w > 0.0f ? v.w : 0.0f;
        *(float4*)&hs[wave * 4 + i][fc * 4] = v;
      }
    }
  }
  __syncthreads();
  if (t < NBH * NCLS) {
    int n = t / NCLS;
    int c = t - n * NCLS;
    float a = b3[c];
    for (int k = 0; k < HID2; k++) a += hs[n][k] * W3l[k * NCLS + c];
    out[(size_t)(node0 + n) * NCLS + c] = a;
  }
}

extern "C" void kernel_launch(void* const* d_in, const int* in_sizes, int n_in,
                              void* d_out, int out_size, void* d_ws, size_t ws_size,
                              hipStream_t stream) {
  const float* x  = (const float*)d_in[0];
  const int*   ei = (const int*)d_in[1];
  const int*   row = ei;
  const int*   col = ei + N_EDGES;
  const float* W1 = (const float*)d_in[3];
  const float* b1 = (const float*)d_in[4];
  const float* W2 = (const float*)d_in[5];
  const float* b2 = (const float*)d_in[6];
  const float* W3 = (const float*)d_in[7];
  const float* b3 = (const float*)d_in[8];
  float* out = (float*)d_out;

  char* ws = (char*)d_ws;
  int*            cursors = (int*)ws;                            // 400 KB
  int*            bcnt    = (int*)(ws + (512 << 10));            // 512 B
  unsigned short* W1t     = (unsigned short*)(ws + (520 << 10)); // 16 KB
  unsigned short* W2t     = (unsigned short*)(ws + (552 << 10)); // 16 KB
  int*            csr_src = (int*)(ws + (1 << 20));              // 25.6 MB
  unsigned int*   pairs   = (unsigned int*)(ws + (28 << 20));    // 7.2 MB
  unsigned short* xb      = (unsigned short*)(ws + (36 << 20));  // 12.8 MB
  unsigned short* g       = (unsigned short*)(ws + (49 << 20));  // 12.8 MB

  // ---- prep: bf16 cast + W transpose + two-level binned CSR build ----
  hipMemsetAsync(bcnt, 0, NBUCK * sizeof(int), stream);
  wtrans_k<<<(IN_F * HID + HID * HID2) / 256, 256, 0, stream>>>(W1, W2, W1t, W2t);
  cast_k<<<N_NODES * IN_F / 8 / 256, 256, 0, stream>>>(x, xb);
  binA_k<<<N_EDGES / EBA, 256, 0, stream>>>(row, col, bcnt, pairs);
  binB_k<<<NBUCK, 512, 0, stream>>>(pairs, bcnt, cursors, csr_src);

  // ---- fused layer 1 + transform: gather -> MFMA mm1 -> MFMA mm2 -> g ----
  gmm1_k<<<N_NODES / NB1, 512, 0, stream>>>(xb, cursors, csr_src, W1t, b1, W2t, g);

  // ---- layer 2 gather + head ----
  ghead_k<<<N_NODES / NBH, 512, 0, stream>>>(g, cursors, csr_src, b2, W3, b3, out);
}